// Round 15
// baseline (247.240 us; speedup 1.0000x reference)
//
#include <hip/hip_runtime.h>

#define NN 200000
#define NE 6400000
#define NB 800            // buckets: dst>>8, 256 nodes each
#define NWA 256           // scatter chunks (1 fat WG per CU)
#define CHUNK 25000       // NE / NWA exactly; single tile per WG
#define BUFCAP 44         // staged records per bucket (λ=31.25, σ=5.6 → +2.4σ; ovf parks rest)
#define CAPB 8704         // fixed per-bucket region in E (mean 8000, σ=89 → 8σ)
#define OVF 256           // overflow pair slots per WG (expected use ≈ 14)

// ws layout (4-byte units)
#define OFF_E    0                        // NB*CAPB = 6,963,200
#define OFF_C    6963200                  // NB: bucket cursors -> totals
#define OFF_RP   6964000                  // NN: CSR row start (absolute into E)
#define OFF_DG   7164000                  // NN: degree
#define OFF_DINV 7364000                  // NN floats
#define OFF_XS   7564000                  // 4*NN floats (16B aligned)
#define OFF_HS2  8364000                  // 4*NN floats (16B aligned)
// end: 9,164,000 ints = 36.7 MB

// Pass A: single-tile scatter (R12-proven form).
__global__ void __launch_bounds__(1024) k_scatter(const int* __restrict__ src,
                                                  const int* __restrict__ dst,
                                                  int* __restrict__ C,
                                                  int* __restrict__ E) {
    __shared__ int wbase[NB];
    __shared__ int cnt[NB];
    __shared__ int buf[NB * BUFCAP];   // 140.8 KB staging (1 WG/CU)
    __shared__ int ovf[2 * OVF];
    __shared__ int ovfn;
    int w = blockIdx.x, t = threadIdx.x;
    for (int b = t; b < NB; b += 1024) cnt[b] = 0;
    if (t == 0) ovfn = 0;
    __syncthreads();
    int lo = w * CHUNK, hi = lo + CHUNK;
    for (int i = lo + t; i < hi; i += 1024) {
        int s = src[i], d = dst[i];
        int b = d >> 8;
        int rec = s | ((d & 255) << 18);
        int pos = atomicAdd(&cnt[b], 1);
        if (pos < BUFCAP) buf[b * BUFCAP + pos] = rec;
        else {
            int o = atomicAdd(&ovfn, 1);
            ovf[2 * o] = rec;
            ovf[2 * o + 1] = (b << 16) | pos;
        }
    }
    __syncthreads();
    for (int b = t; b < NB; b += 1024)
        wbase[b] = b * CAPB + atomicAdd(&C[b], cnt[b]);
    __syncthreads();
    for (int idx = t; idx < NB * BUFCAP; idx += 1024) {
        int b = idx / BUFCAP, j = idx - b * BUFCAP;
        int c = cnt[b];
        if (j < (c < BUFCAP ? c : BUFCAP)) E[wbase[b] + j] = buf[idx];
    }
    for (int o = t; o < ovfn; o += 1024) {
        int rec = ovf[2 * o], bp = ovf[2 * o + 1];
        E[wbase[bp >> 16] + (bp & 0xFFFF)] = rec;
    }
}

// Pass B: rank-based counting sort into CSR. The count-phase atomic's return
// value IS each record's within-bin rank (uchar, max degree ~70) — the
// permute phase is then atomic-free: E[lo + excl[bin] + rank] = src.
// Emits RP, DG, dinv, xs = x*dinv.
__global__ void __launch_bounds__(512) k_sort(const float* __restrict__ x, int* __restrict__ E,
                       const int* __restrict__ C,
                       int* __restrict__ RP, int* __restrict__ DG,
                       float* __restrict__ dinv, float4* __restrict__ xs4) {
    __shared__ int stg[CAPB];              // 34.8 KB
    __shared__ unsigned char rnk[CAPB];    // 8.7 KB
    __shared__ int cnt[256];
    __shared__ int pos[256];
    int b = blockIdx.x, t = threadIdx.x;
    int lo = b * CAPB;
    int n = C[b];
    if (t < 256) cnt[t] = 0;
    __syncthreads();
    for (int i = t; i < n; i += 512) {
        int r = E[lo + i];
        stg[i] = r;
        rnk[i] = (unsigned char)atomicAdd(&cnt[r >> 18], 1);
    }
    __syncthreads();
    if (t < 256) pos[t] = cnt[t];
    __syncthreads();
    for (int off = 1; off < 256; off <<= 1) {
        int v = 0;
        if (t < 256 && t >= off) v = pos[t - off];
        __syncthreads();
        if (t < 256) pos[t] += v;
        __syncthreads();
    }
    if (t < 256) {
        int c = cnt[t];
        int excl = pos[t] - c;
        int node = (b << 8) + t;
        if (node < NN) {
            RP[node] = lo + excl;
            DG[node] = c;
            float di = rsqrtf(1.0f + (float)c);
            dinv[node] = di;
            xs4[node] = make_float4(x[3 * node] * di, x[3 * node + 1] * di,
                                    x[3 * node + 2] * di, 0.f);
        }
        cnt[t] = excl;   // excl per bin for the permute phase
    }
    __syncthreads();
    for (int i = t; i < n; i += 512) {
        int rec = stg[i];
        int bin = rec >> 18;
        E[lo + cnt[bin] + (int)rnk[i]] = rec & 0x3FFFF;   // CSR: src only
    }
}

// Pass C: layer-1 gather, 16 lanes per node (R12-proven form)
// + fused dense W1/b1/relu/W2 -> hs2 (LDS write-combined store)
__global__ void k_gather1(const int* __restrict__ E, const int* __restrict__ RP,
                          const int* __restrict__ DG, const float* __restrict__ dinv,
                          const float4* __restrict__ xs4, const float* __restrict__ W1,
                          const float* __restrict__ b1, const float* __restrict__ W2,
                          float4* __restrict__ hs24) {
    __shared__ float sW1[48], sb1[16], sW2[48];
    __shared__ float4 sm4[16];
    int t = threadIdx.x;
    if (t < 48) sW1[t] = W1[t];
    else if (t < 64) sb1[t - 48] = b1[t - 48];
    else if (t < 112) sW2[t - 64] = W2[t - 64];
    __syncthreads();
    int seg = t >> 4, lane = t & 15;
    int n = blockIdx.x * 16 + seg;        // grid*16 == NN exactly
    int rp = RP[n], dg = DG[n];
    float s0 = 0.f, s1 = 0.f, s2 = 0.f;
    for (int j = lane; j < dg; j += 16) {
        float4 m = xs4[E[rp + j]];
        s0 += m.x; s1 += m.y; s2 += m.z;
    }
#pragma unroll
    for (int msk = 1; msk < 16; msk <<= 1) {
        s0 += __shfl_xor(s0, msk, 16);
        s1 += __shfl_xor(s1, msk, 16);
        s2 += __shfl_xor(s2, msk, 16);
    }
    if (lane == 0) {
        float di = dinv[n];
        float4 self = xs4[n];
        float a0 = di * (s0 + self.x);
        float a1 = di * (s1 + self.y);
        float a2 = di * (s2 + self.z);
        float h1[16];
#pragma unroll
        for (int k = 0; k < 16; ++k) {
            float v = a0 * sW1[k] + a1 * sW1[16 + k] + a2 * sW1[32 + k] + sb1[k];
            h1[k] = v > 0.f ? v : 0.f;
        }
        float o0 = 0.f, o1 = 0.f, o2 = 0.f;
#pragma unroll
        for (int k = 0; k < 16; ++k) {
            o0 += h1[k] * sW2[3 * k + 0];
            o1 += h1[k] * sW2[3 * k + 1];
            o2 += h1[k] * sW2[3 * k + 2];
        }
        sm4[seg] = make_float4(o0 * di, o1 * di, o2 * di, 0.f);
    }
    __syncthreads();
    if (t < 64) {
        float* dstf = (float*)(hs24 + (size_t)blockIdx.x * 16);
        dstf[t] = ((const float*)sm4)[t];
    }
}

// Pass D: layer-2 gather, 16 lanes per node + bias -> out (LDS write-combined)
__global__ void k_gather2(const int* __restrict__ E, const int* __restrict__ RP,
                          const int* __restrict__ DG, const float* __restrict__ dinv,
                          const float4* __restrict__ hs24, const float* __restrict__ b2,
                          float* __restrict__ out) {
    __shared__ float smo[48];
    int t = threadIdx.x;
    int seg = t >> 4, lane = t & 15;
    int n = blockIdx.x * 16 + seg;
    int rp = RP[n], dg = DG[n];
    float s0 = 0.f, s1 = 0.f, s2 = 0.f;
    for (int j = lane; j < dg; j += 16) {
        float4 m = hs24[E[rp + j]];
        s0 += m.x; s1 += m.y; s2 += m.z;
    }
#pragma unroll
    for (int msk = 1; msk < 16; msk <<= 1) {
        s0 += __shfl_xor(s0, msk, 16);
        s1 += __shfl_xor(s1, msk, 16);
        s2 += __shfl_xor(s2, msk, 16);
    }
    if (lane == 0) {
        float di = dinv[n];
        float4 self = hs24[n];
        smo[seg * 3 + 0] = di * (s0 + self.x) + b2[0];
        smo[seg * 3 + 1] = di * (s1 + self.y) + b2[1];
        smo[seg * 3 + 2] = di * (s2 + self.z) + b2[2];
    }
    __syncthreads();
    if (t < 48) out[(size_t)blockIdx.x * 48 + t] = smo[t];
}

extern "C" void kernel_launch(void* const* d_in, const int* in_sizes, int n_in,
                              void* d_out, int out_size, void* d_ws, size_t ws_size,
                              hipStream_t stream) {
    const float* x  = (const float*)d_in[0];
    const int* ei   = (const int*)d_in[1];
    const float* W1 = (const float*)d_in[2];
    const float* b1 = (const float*)d_in[3];
    const float* W2 = (const float*)d_in[4];
    const float* b2 = (const float*)d_in[5];
    const int* src = ei;
    const int* dst = ei + NE;
    float* ws = (float*)d_ws;
    int* wsi = (int*)d_ws;
    float* out = (float*)d_out;

    int* E      = wsi + OFF_E;
    int* C      = wsi + OFF_C;
    int* RP     = wsi + OFF_RP;
    int* DG     = wsi + OFF_DG;
    float* dinv = ws + OFF_DINV;
    float4* xs4 = (float4*)(ws + OFF_XS);
    float4* hs24 = (float4*)(ws + OFF_HS2);

    hipMemsetAsync(C, 0, NB * sizeof(int), stream);
    k_scatter<<<NWA, 1024, 0, stream>>>(src, dst, C, E);
    k_sort<<<NB, 512, 0, stream>>>(x, E, C, RP, DG, dinv, xs4);
    k_gather1<<<NN / 16, 256, 0, stream>>>(E, RP, DG, dinv, xs4, W1, b1, W2, hs24);
    k_gather2<<<NN / 16, 256, 0, stream>>>(E, RP, DG, dinv, hs24, b2, out);
}

// Round 16
// 238.981 us; speedup vs baseline: 1.0346x; 1.0346x over previous
//
#include <hip/hip_runtime.h>

#define NN 200000
#define NE 6400000
#define NB 800            // buckets: dst>>8, 256 nodes each
#define NWA 256           // scatter chunks (1 fat WG per CU)
#define CHUNK 25000       // NE / NWA exactly; single tile per WG
#define BUFCAP 44         // staged records per bucket (λ=31.25, σ=5.6 → +2.4σ; ovf parks rest)
#define CAPB 8704         // fixed per-bucket region in E (mean 8000, σ=89 → 8σ)
#define OVF 256           // overflow pair slots per WG (expected use ≈ 14)

// ws layout (4-byte units)
#define OFF_E    0                        // NB*CAPB = 6,963,200
#define OFF_C    6963200                  // NB: bucket cursors -> totals
#define OFF_RP   6964000                  // NN: CSR row start (absolute into E)
#define OFF_DG   7164000                  // NN: degree
#define OFF_DINV 7364000                  // NN floats
#define OFF_XS   7564000                  // 4*NN floats (16B aligned)
#define OFF_HS2  8364000                  // 4*NN floats (16B aligned)
// end: 9,164,000 ints = 36.7 MB

// Pass A: single-tile scatter (R12-proven form: ~31-record streams minimize
// random-line store transactions — the measured controlling variable).
__global__ void __launch_bounds__(1024) k_scatter(const int* __restrict__ src,
                                                  const int* __restrict__ dst,
                                                  int* __restrict__ C,
                                                  int* __restrict__ E) {
    __shared__ int wbase[NB];
    __shared__ int cnt[NB];
    __shared__ int buf[NB * BUFCAP];   // 140.8 KB staging (1 WG/CU)
    __shared__ int ovf[2 * OVF];
    __shared__ int ovfn;
    int w = blockIdx.x, t = threadIdx.x;
    for (int b = t; b < NB; b += 1024) cnt[b] = 0;
    if (t == 0) ovfn = 0;
    __syncthreads();
    int lo = w * CHUNK, hi = lo + CHUNK;
    for (int i = lo + t; i < hi; i += 1024) {
        int s = src[i], d = dst[i];
        int b = d >> 8;
        int rec = s | ((d & 255) << 18);
        int pos = atomicAdd(&cnt[b], 1);
        if (pos < BUFCAP) buf[b * BUFCAP + pos] = rec;
        else {
            int o = atomicAdd(&ovfn, 1);
            ovf[2 * o] = rec;
            ovf[2 * o + 1] = (b << 16) | pos;
        }
    }
    __syncthreads();
    for (int b = t; b < NB; b += 1024)
        wbase[b] = b * CAPB + atomicAdd(&C[b], cnt[b]);
    __syncthreads();
    for (int idx = t; idx < NB * BUFCAP; idx += 1024) {
        int b = idx / BUFCAP, j = idx - b * BUFCAP;
        int c = cnt[b];
        if (j < (c < BUFCAP ? c : BUFCAP)) E[wbase[b] + j] = buf[idx];
    }
    for (int o = t; o < ovfn; o += 1024) {
        int rec = ovf[2 * o], bp = ovf[2 * o + 1];
        E[wbase[bp >> 16] + (bp & 0xFFFF)] = rec;
    }
}

// Pass B: per-bucket counting sort into CSR (R12-proven form: cursor atomics,
// ~37 KB LDS -> 4 WG/CU, single dispatch round). Emits RP, DG, dinv, xs.
__global__ void __launch_bounds__(512) k_sort(const float* __restrict__ x, int* __restrict__ E,
                       const int* __restrict__ C,
                       int* __restrict__ RP, int* __restrict__ DG,
                       float* __restrict__ dinv, float4* __restrict__ xs4) {
    __shared__ int stg[CAPB];          // 34.8 KB
    __shared__ int cnt[256];
    __shared__ int pos[256];
    int b = blockIdx.x, t = threadIdx.x;
    int lo = b * CAPB;
    int n = C[b];
    if (t < 256) cnt[t] = 0;
    __syncthreads();
    for (int i = t; i < n; i += 512) {
        int r = E[lo + i];
        stg[i] = r;
        atomicAdd(&cnt[r >> 18], 1);
    }
    __syncthreads();
    if (t < 256) pos[t] = cnt[t];
    __syncthreads();
    for (int off = 1; off < 256; off <<= 1) {
        int v = 0;
        if (t < 256 && t >= off) v = pos[t - off];
        __syncthreads();
        if (t < 256) pos[t] += v;
        __syncthreads();
    }
    if (t < 256) {
        int c = cnt[t];
        int excl = pos[t] - c;
        int node = (b << 8) + t;
        if (node < NN) {
            RP[node] = lo + excl;
            DG[node] = c;
            float di = rsqrtf(1.0f + (float)c);
            dinv[node] = di;
            xs4[node] = make_float4(x[3 * node] * di, x[3 * node + 1] * di,
                                    x[3 * node + 2] * di, 0.f);
        }
        cnt[t] = excl;   // becomes the scatter cursor
    }
    __syncthreads();
    for (int i = t; i < n; i += 512) {
        int rec = stg[i];
        int l = rec >> 18;
        int slot = atomicAdd(&cnt[l], 1);
        E[lo + slot] = rec & 0x3FFFF;   // CSR: src only
    }
}

// Pass C: layer-1 gather, 16 lanes per node (R12-proven form)
// + fused dense W1/b1/relu/W2 -> hs2 (LDS write-combined store)
__global__ void k_gather1(const int* __restrict__ E, const int* __restrict__ RP,
                          const int* __restrict__ DG, const float* __restrict__ dinv,
                          const float4* __restrict__ xs4, const float* __restrict__ W1,
                          const float* __restrict__ b1, const float* __restrict__ W2,
                          float4* __restrict__ hs24) {
    __shared__ float sW1[48], sb1[16], sW2[48];
    __shared__ float4 sm4[16];
    int t = threadIdx.x;
    if (t < 48) sW1[t] = W1[t];
    else if (t < 64) sb1[t - 48] = b1[t - 48];
    else if (t < 112) sW2[t - 64] = W2[t - 64];
    __syncthreads();
    int seg = t >> 4, lane = t & 15;
    int n = blockIdx.x * 16 + seg;        // grid*16 == NN exactly
    int rp = RP[n], dg = DG[n];
    float s0 = 0.f, s1 = 0.f, s2 = 0.f;
    for (int j = lane; j < dg; j += 16) {
        float4 m = xs4[E[rp + j]];
        s0 += m.x; s1 += m.y; s2 += m.z;
    }
#pragma unroll
    for (int msk = 1; msk < 16; msk <<= 1) {
        s0 += __shfl_xor(s0, msk, 16);
        s1 += __shfl_xor(s1, msk, 16);
        s2 += __shfl_xor(s2, msk, 16);
    }
    if (lane == 0) {
        float di = dinv[n];
        float4 self = xs4[n];
        float a0 = di * (s0 + self.x);
        float a1 = di * (s1 + self.y);
        float a2 = di * (s2 + self.z);
        float h1[16];
#pragma unroll
        for (int k = 0; k < 16; ++k) {
            float v = a0 * sW1[k] + a1 * sW1[16 + k] + a2 * sW1[32 + k] + sb1[k];
            h1[k] = v > 0.f ? v : 0.f;
        }
        float o0 = 0.f, o1 = 0.f, o2 = 0.f;
#pragma unroll
        for (int k = 0; k < 16; ++k) {
            o0 += h1[k] * sW2[3 * k + 0];
            o1 += h1[k] * sW2[3 * k + 1];
            o2 += h1[k] * sW2[3 * k + 2];
        }
        sm4[seg] = make_float4(o0 * di, o1 * di, o2 * di, 0.f);
    }
    __syncthreads();
    if (t < 64) {
        float* dstf = (float*)(hs24 + (size_t)blockIdx.x * 16);
        dstf[t] = ((const float*)sm4)[t];
    }
}

// Pass D: layer-2 gather, 16 lanes per node + bias -> out (LDS write-combined)
__global__ void k_gather2(const int* __restrict__ E, const int* __restrict__ RP,
                          const int* __restrict__ DG, const float* __restrict__ dinv,
                          const float4* __restrict__ hs24, const float* __restrict__ b2,
                          float* __restrict__ out) {
    __shared__ float smo[48];
    int t = threadIdx.x;
    int seg = t >> 4, lane = t & 15;
    int n = blockIdx.x * 16 + seg;
    int rp = RP[n], dg = DG[n];
    float s0 = 0.f, s1 = 0.f, s2 = 0.f;
    for (int j = lane; j < dg; j += 16) {
        float4 m = hs24[E[rp + j]];
        s0 += m.x; s1 += m.y; s2 += m.z;
    }
#pragma unroll
    for (int msk = 1; msk < 16; msk <<= 1) {
        s0 += __shfl_xor(s0, msk, 16);
        s1 += __shfl_xor(s1, msk, 16);
        s2 += __shfl_xor(s2, msk, 16);
    }
    if (lane == 0) {
        float di = dinv[n];
        float4 self = hs24[n];
        smo[seg * 3 + 0] = di * (s0 + self.x) + b2[0];
        smo[seg * 3 + 1] = di * (s1 + self.y) + b2[1];
        smo[seg * 3 + 2] = di * (s2 + self.z) + b2[2];
    }
    __syncthreads();
    if (t < 48) out[(size_t)blockIdx.x * 48 + t] = smo[t];
}

extern "C" void kernel_launch(void* const* d_in, const int* in_sizes, int n_in,
                              void* d_out, int out_size, void* d_ws, size_t ws_size,
                              hipStream_t stream) {
    const float* x  = (const float*)d_in[0];
    const int* ei   = (const int*)d_in[1];
    const float* W1 = (const float*)d_in[2];
    const float* b1 = (const float*)d_in[3];
    const float* W2 = (const float*)d_in[4];
    const float* b2 = (const float*)d_in[5];
    const int* src = ei;
    const int* dst = ei + NE;
    float* ws = (float*)d_ws;
    int* wsi = (int*)d_ws;
    float* out = (float*)d_out;

    int* E      = wsi + OFF_E;
    int* C      = wsi + OFF_C;
    int* RP     = wsi + OFF_RP;
    int* DG     = wsi + OFF_DG;
    float* dinv = ws + OFF_DINV;
    float4* xs4 = (float4*)(ws + OFF_XS);
    float4* hs24 = (float4*)(ws + OFF_HS2);

    hipMemsetAsync(C, 0, NB * sizeof(int), stream);
    k_scatter<<<NWA, 1024, 0, stream>>>(src, dst, C, E);
    k_sort<<<NB, 512, 0, stream>>>(x, E, C, RP, DG, dinv, xs4);
    k_gather1<<<NN / 16, 256, 0, stream>>>(E, RP, DG, dinv, xs4, W1, b1, W2, hs24);
    k_gather2<<<NN / 16, 256, 0, stream>>>(E, RP, DG, dinv, hs24, b2, out);
}